// Round 4
// baseline (3290.885 us; speedup 1.0000x reference)
//
#include <hip/hip_runtime.h>
#include <math.h>

// ---------------- constants ----------------
#define SEQ 128
#define BATCH 256
#define INPUT 300
#define HIDDEN 1024
#define NG 4096              // 4*HIDDEN, gate-interleaved: n' = 4*j + gate
#define KH 1024
#define KXP 320              // x K padded 300->320
#define NKT 42               // (KH+KXP)/32 k-tiles in recurrent GEMM
#define KTH 32               // KH/32 h k-tiles
#define NKTX 10              // KXP/32 x k-tiles
#define NKTH 32              // head k-tiles (K=1024)
#define LINEARN 1024

// fragment-major layouts: chunk(tile, lane) = 8 contiguous shorts;
//   elem (row, k): tile = (row/16)*ntiles_k + k/32 ; lane = ((k>>3)&3)*16 + (row&15); off = k&7
// A wave-load of chunk base + lane*8 is one fully-coalesced 1KB global_load_dwordx4.

typedef __attribute__((ext_vector_type(8))) short short8;
typedef __attribute__((ext_vector_type(4))) float floatx4;

__device__ __forceinline__ float sigf(float x)     { return 1.f / (1.f + __expf(-x)); }
__device__ __forceinline__ float tanhfast(float x) { return 2.f / (1.f + __expf(-2.f * x)) - 1.f; }

__device__ __forceinline__ unsigned short bf16_rne(float f) {
  unsigned u = __float_as_uint(f);
  u += 0x7FFFu + ((u >> 16) & 1u);
  return (unsigned short)(u >> 16);
}
__device__ __forceinline__ float bf16f(unsigned short s) {
  return __uint_as_float(((unsigned)s) << 16);
}

__device__ __forceinline__ void mfma3(floatx4& acc, short8 ah, short8 al, short8 bh, short8 bl) {
  acc = __builtin_amdgcn_mfma_f32_16x16x32_bf16(ah, bh, acc, 0, 0, 0);
  acc = __builtin_amdgcn_mfma_f32_16x16x32_bf16(ah, bl, acc, 0, 0, 0);
  acc = __builtin_amdgcn_mfma_f32_16x16x32_bf16(al, bh, acc, 0, 0, 0);
}

// ---------------- zero ----------------
__global__ __launch_bounds__(256) void zero_ws(float4* p, int n4) {
  int i = blockIdx.x * 256 + threadIdx.x;
  if (i < n4) p[i] = make_float4(0.f, 0.f, 0.f, 0.f);
}

// ---------------- pack W (gate-interleave + fragment-major + hi/lo split) ----------------
// Wf: [ntile(256)][kt(42)][lane(64)][8]
__global__ __launch_bounds__(256) void pack_w(
    const float* __restrict__ W_ih, const float* __restrict__ W_hh,
    unsigned short* __restrict__ Wfh, unsigned short* __restrict__ Wfl)
{
  int id = blockIdx.x * 256 + threadIdx.x;
  if (id >= (NG / 16) * NKT * 512) return;
  int e    = id & 7;
  int lane = (id >> 3) & 63;
  int rest = id >> 9;            // ntile*NKT + kt
  int kt   = rest % NKT;
  int ntile = rest / NKT;
  int n = ntile * 16 + (lane & 15);          // n' = 4*j + g
  int k = kt * 32 + (lane >> 4) * 8 + e;
  int j = n >> 2, g = n & 3;
  int srow = g * HIDDEN + j;
  float w = 0.f;
  if (k < KH) w = W_hh[(size_t)srow * HIDDEN + k];
  else if (k - KH < INPUT) w = W_ih[(size_t)srow * INPUT + (k - KH)];
  unsigned short hi = bf16_rne(w);
  Wfh[id] = hi;
  Wfl[id] = bf16_rne(w - bf16f(hi));
}

__global__ __launch_bounds__(256) void pack_bias(
    const float* __restrict__ b_ih, const float* __restrict__ b_hh,
    float* __restrict__ biasp)
{
  int n = blockIdx.x * 256 + threadIdx.x;
  if (n >= NG) return;
  int j = n >> 2, g = n & 3;
  int s = g * HIDDEN + j;
  biasp[n] = b_ih[s] + b_hh[s];
}

// ---------------- pack x: fragment-major per step ----------------
// xf: [step(128)][mtile(16)][ktx(10)][lane(64)][8]
__global__ __launch_bounds__(256) void pack_x(
    const float* __restrict__ x, unsigned short* __restrict__ xfh,
    unsigned short* __restrict__ xfl)
{
  int id = blockIdx.x * 256 + threadIdx.x;
  if (id >= SEQ * 16 * NKTX * 512) return;
  int e    = id & 7;
  int lane = (id >> 3) & 63;
  int rest = id >> 9;                    // (step*16 + mtile)*10 + ktx
  int ktx  = rest % NKTX;
  int mt_  = rest / NKTX;
  int mtile = mt_ & 15;
  int step  = mt_ >> 4;
  int m = mtile * 16 + (lane & 15);
  int j = ktx * 32 + (lane >> 4) * 8 + e;
  float v = (j < INPUT) ? x[((size_t)step * BATCH + m) * INPUT + j] : 0.f;
  unsigned short hi = bf16_rne(v);
  xfh[id] = hi;
  xfl[id] = bf16_rne(v - bf16f(hi));
}

// ---------------- pack W1: fragment-major ----------------
// W1f: [ntile(64)][kt(32)][lane(64)][8]
__global__ __launch_bounds__(256) void pack_w1(
    const float* __restrict__ W1, unsigned short* __restrict__ W1fh,
    unsigned short* __restrict__ W1fl)
{
  int id = blockIdx.x * 256 + threadIdx.x;
  if (id >= (LINEARN / 16) * NKTH * 512) return;
  int e    = id & 7;
  int lane = (id >> 3) & 63;
  int rest = id >> 9;
  int kt   = rest % NKTH;
  int ntile = rest / NKTH;
  int n = ntile * 16 + (lane & 15);
  int k = kt * 32 + (lane >> 4) * 8 + e;
  float w = W1[(size_t)n * HIDDEN + k];
  unsigned short hi = bf16_rne(w);
  W1fh[id] = hi;
  W1fl[id] = bf16_rne(w - bf16f(hi));
}

// ---------------- fused LSTM step: barrier-free K-loop, direct fragment loads ----------------
// grid (64 jtiles, 4 mtiles), 256 threads, wave grid 2x2, wave tile 32x32.
__global__ __launch_bounds__(256) void lstm_step(
    const unsigned short* __restrict__ xfh,     // this step's x frags [16][10][512]
    const unsigned short* __restrict__ xfl,
    const unsigned short* __restrict__ hfh_r,   // h frags [16][32][512]
    const unsigned short* __restrict__ hfl_r,
    const unsigned short* __restrict__ Wfh,     // [256][42][512]
    const unsigned short* __restrict__ Wfl,
    const float* __restrict__ biasp,            // [4096]
    float* __restrict__ cst,                    // [256][1024] fp32
    unsigned short* __restrict__ hfh_w,
    unsigned short* __restrict__ hfl_w)
{
  __shared__ float epi[64 * 65];

  const int t    = threadIdx.x;
  const int lane = t & 63;
  const int wave = t >> 6;
  const int wm   = (wave >> 1) * 32;           // wave m origin within tile
  const int wn   = (wave & 1) * 32;
  const int col  = lane & 15;
  const int quad = lane >> 4;
  const int m0   = blockIdx.y * 64;
  const int n0   = blockIdx.x * 64;
  const int j0   = blockIdx.x * 16;
  const int mta  = blockIdx.y * 4 + (wm >> 4); // global mtile base for this wave (2 tiles)
  const int nta  = blockIdx.x * 4 + (wn >> 4); // global ntile base for this wave (2 tiles)

  // hoisted epilogue operands
  const int mloc = t >> 2;
  const int jl4  = (t & 3) * 4;
  const int m    = m0 + mloc;
  const int j    = j0 + jl4;
  float4 cold = *(const float4*)(cst + (size_t)m * HIDDEN + j);
  float bb0 = biasp[n0 + wn + col];
  float bb1 = biasp[n0 + wn + 16 + col];

  floatx4 acc[2][2];
#pragma unroll
  for (int i = 0; i < 2; ++i)
#pragma unroll
    for (int jj = 0; jj < 2; ++jj)
      acc[i][jj] = (floatx4){0.f, 0.f, 0.f, 0.f};

  // F: [0]=ah0 [1]=ah1 [2]=al0 [3]=al1 [4]=bh0 [5]=bh1 [6]=bl0 [7]=bl1
#define LOADK(kt, F) do {                                                     \
    if ((kt) < KTH) {                                                         \
      const size_t ao = ((size_t)(mta * KTH + (kt)) << 9) + lane * 8;         \
      F[0] = *(const short8*)(hfh_r + ao);                                    \
      F[1] = *(const short8*)(hfh_r + ao + (KTH << 9));                       \
      F[2] = *(const short8*)(hfl_r + ao);                                    \
      F[3] = *(const short8*)(hfl_r + ao + (KTH << 9));                       \
    } else {                                                                  \
      const size_t ao = ((size_t)(mta * NKTX + (kt) - KTH) << 9) + lane * 8;  \
      F[0] = *(const short8*)(xfh + ao);                                      \
      F[1] = *(const short8*)(xfh + ao + (NKTX << 9));                        \
      F[2] = *(const short8*)(xfl + ao);                                      \
      F[3] = *(const short8*)(xfl + ao + (NKTX << 9));                        \
    }                                                                         \
    { const size_t bo = ((size_t)(nta * NKT + (kt)) << 9) + lane * 8;         \
      F[4] = *(const short8*)(Wfh + bo);                                      \
      F[5] = *(const short8*)(Wfh + bo + (NKT << 9));                         \
      F[6] = *(const short8*)(Wfl + bo);                                      \
      F[7] = *(const short8*)(Wfl + bo + (NKT << 9)); }                       \
  } while (0)

#define DOMFMA(F) do {                                                        \
    mfma3(acc[0][0], F[0], F[2], F[4], F[6]);                                 \
    mfma3(acc[0][1], F[0], F[2], F[5], F[7]);                                 \
    mfma3(acc[1][0], F[1], F[3], F[4], F[6]);                                 \
    mfma3(acc[1][1], F[1], F[3], F[5], F[7]);                                 \
  } while (0)

  short8 f0[8], f1[8];
  LOADK(0, f0);
  for (int kt = 0; kt < NKT; kt += 2) {
    LOADK(kt + 1, f1);
    DOMFMA(f0);
    if (kt + 2 < NKT) LOADK(kt + 2, f0);
    DOMFMA(f1);
  }
#undef LOADK
#undef DOMFMA

  // ---- epilogue: gates -> LDS [n'][m], fused cell update ----
#pragma unroll
  for (int mt = 0; mt < 2; ++mt)
#pragma unroll
    for (int nt = 0; nt < 2; ++nt) {
      const int nl = wn + nt * 16 + col;
      const float bb = nt ? bb1 : bb0;
#pragma unroll
      for (int reg = 0; reg < 4; ++reg) {
        const int ml = wm + mt * 16 + quad * 4 + reg;
        epi[nl * 65 + ml] = acc[mt][nt][reg] + bb;
      }
    }
  __syncthreads();

  float cn[4], hn[4];
#pragma unroll
  for (int jj = 0; jj < 4; ++jj) {
    const int nl = (jl4 + jj) * 4;
    const float gi = epi[(nl + 0) * 65 + mloc];
    const float gf = epi[(nl + 1) * 65 + mloc];
    const float gg = epi[(nl + 2) * 65 + mloc];
    const float go = epi[(nl + 3) * 65 + mloc];
    const float cc = (jj == 0) ? cold.x : (jj == 1) ? cold.y : (jj == 2) ? cold.z : cold.w;
    const float cnew = sigf(gf) * cc + sigf(gi) * tanhfast(gg);
    cn[jj] = cnew;
    hn[jj] = sigf(go) * tanhfast(cnew);
  }
  *(float4*)(cst + (size_t)m * HIDDEN + j) = make_float4(cn[0], cn[1], cn[2], cn[3]);

  // h store in fragment-major layout for next step's A loads
  ushort4 uh, ul;
  uh.x = bf16_rne(hn[0]); uh.y = bf16_rne(hn[1]); uh.z = bf16_rne(hn[2]); uh.w = bf16_rne(hn[3]);
  ul.x = bf16_rne(hn[0] - bf16f(uh.x));
  ul.y = bf16_rne(hn[1] - bf16f(uh.y));
  ul.z = bf16_rne(hn[2] - bf16f(uh.z));
  ul.w = bf16_rne(hn[3] - bf16f(uh.w));
  const int tile  = (m >> 4) * KTH + (j >> 5);
  const int lane2 = ((j >> 3) & 3) * 16 + (m & 15);
  const size_t ha = ((size_t)(tile * 64 + lane2) << 3) + (j & 7);
  *(ushort4*)(hfh_w + ha) = uh;
  *(ushort4*)(hfl_w + ha) = ul;
}

// ---------------- head GEMM: z = h @ W1^T + b1, same barrier-free structure ----------------
__global__ __launch_bounds__(256) void head_gemm(
    const unsigned short* __restrict__ hfh,     // final h frags [16][32][512]
    const unsigned short* __restrict__ hfl,
    const unsigned short* __restrict__ W1fh,    // [64][32][512]
    const unsigned short* __restrict__ W1fl,
    const float* __restrict__ bias,
    float* __restrict__ C)                      // z [256][1024]
{
  const int t    = threadIdx.x;
  const int lane = t & 63;
  const int wave = t >> 6;
  const int wm   = (wave >> 1) * 32;
  const int wn   = (wave & 1) * 32;
  const int col  = lane & 15;
  const int quad = lane >> 4;
  const int m0   = blockIdx.y * 64;
  const int n0   = blockIdx.x * 64;
  const int mta  = blockIdx.y * 4 + (wm >> 4);
  const int nta  = blockIdx.x * 4 + (wn >> 4);

  floatx4 acc[2][2];
#pragma unroll
  for (int i = 0; i < 2; ++i)
#pragma unroll
    for (int jj = 0; jj < 2; ++jj)
      acc[i][jj] = (floatx4){0.f, 0.f, 0.f, 0.f};

#define LOADK(kt, F) do {                                                     \
    const size_t ao = ((size_t)(mta * NKTH + (kt)) << 9) + lane * 8;          \
    F[0] = *(const short8*)(hfh + ao);                                        \
    F[1] = *(const short8*)(hfh + ao + (NKTH << 9));                          \
    F[2] = *(const short8*)(hfl + ao);                                        \
    F[3] = *(const short8*)(hfl + ao + (NKTH << 9));                          \
    const size_t bo = ((size_t)(nta * NKTH + (kt)) << 9) + lane * 8;          \
    F[4] = *(const short8*)(W1fh + bo);                                       \
    F[5] = *(const short8*)(W1fh + bo + (NKTH << 9));                         \
    F[6] = *(const short8*)(W1fl + bo);                                       \
    F[7] = *(const short8*)(W1fl + bo + (NKTH << 9));                         \
  } while (0)

#define DOMFMA(F) do {                                                        \
    mfma3(acc[0][0], F[0], F[2], F[4], F[6]);                                 \
    mfma3(acc[0][1], F[0], F[2], F[5], F[7]);                                 \
    mfma3(acc[1][0], F[1], F[3], F[4], F[6]);                                 \
    mfma3(acc[1][1], F[1], F[3], F[5], F[7]);                                 \
  } while (0)

  short8 f0[8], f1[8];
  LOADK(0, f0);
  for (int kt = 0; kt < NKTH; kt += 2) {
    LOADK(kt + 1, f1);
    DOMFMA(f0);
    if (kt + 2 < NKTH) LOADK(kt + 2, f0);
    DOMFMA(f1);
  }
#undef LOADK
#undef DOMFMA

#pragma unroll
  for (int mt = 0; mt < 2; ++mt)
#pragma unroll
    for (int nt = 0; nt < 2; ++nt) {
      const int nl = n0 + wn + nt * 16 + col;
      const float bb = bias[nl];
#pragma unroll
      for (int reg = 0; reg < 4; ++reg) {
        const int ml = m0 + wm + mt * 16 + quad * 4 + reg;
        C[(size_t)ml * LINEARN + nl] = acc[mt][nt][reg] + bb;
      }
    }
}

// ---------------- BN stats ----------------
__global__ __launch_bounds__(64) void bn_stats(
    const float* __restrict__ z, float* __restrict__ mean, float* __restrict__ rstd)
{
  const int n = blockIdx.x;
  const int t = threadIdx.x;
  float s = 0.f, s2 = 0.f;
  for (int r = t; r < BATCH; r += 64) {
    const float v = z[(size_t)r * LINEARN + n];
    s += v; s2 += v * v;
  }
#pragma unroll
  for (int off = 32; off > 0; off >>= 1) {
    s  += __shfl_down(s,  off, 64);
    s2 += __shfl_down(s2, off, 64);
  }
  if (t == 0) {
    const float mm = s * (1.f / BATCH);
    mean[n] = mm;
    rstd[n] = rsqrtf(s2 * (1.f / BATCH) - mm * mm + 1e-5f);
  }
}

// ---------------- head out ----------------
__global__ __launch_bounds__(256) void head_out(
    const float* __restrict__ z, const float* __restrict__ mean, const float* __restrict__ rstd,
    const float* __restrict__ gamma, const float* __restrict__ beta,
    const float* __restrict__ W2, const float* __restrict__ b2, float* __restrict__ out)
{
  const int b = blockIdx.x;
  const int t = threadIdx.x;
  float acc = 0.f;
  for (int n = t; n < LINEARN; n += 256) {
    float v = (z[(size_t)b * LINEARN + n] - mean[n]) * rstd[n] * gamma[n] + beta[n];
    v = fmaxf(v, 0.f);
    acc += v * W2[n];
  }
#pragma unroll
  for (int off = 32; off > 0; off >>= 1) acc += __shfl_down(acc, off, 64);
  __shared__ float ls[4];
  if ((t & 63) == 0) ls[t >> 6] = acc;
  __syncthreads();
  if (t == 0) {
    const float tot = ls[0] + ls[1] + ls[2] + ls[3] + b2[0];
    out[b] = 3.f / (1.f + __expf(-tot));
  }
}

// ---------------- launch ----------------
extern "C" void kernel_launch(void* const* d_in, const int* in_sizes, int n_in,
                              void* d_out, int out_size, void* d_ws, size_t ws_size,
                              hipStream_t stream) {
  const float* x     = (const float*)d_in[0];
  const float* W_ih  = (const float*)d_in[1];
  const float* W_hh  = (const float*)d_in[2];
  const float* b_ih  = (const float*)d_in[3];
  const float* b_hh  = (const float*)d_in[4];
  const float* W1    = (const float*)d_in[5];
  const float* b1    = (const float*)d_in[6];
  const float* gamma = (const float*)d_in[7];
  const float* beta  = (const float*)d_in[8];
  const float* W2    = (const float*)d_in[9];
  const float* b2    = (const float*)d_in[10];
  float* out = (float*)d_out;

  char* w = (char*)d_ws;
  // zero region (contiguous 2 MB): hf0 hi, hf0 lo, c
  unsigned short* hfh0 = (unsigned short*)(w + 0);          // 512 KB
  unsigned short* hfl0 = (unsigned short*)(w + 524288);     // 512 KB
  float*          cst  = (float*)(w + 1048576);             // 1 MB
  unsigned short* hfh1 = (unsigned short*)(w + 2097152);
  unsigned short* hfl1 = (unsigned short*)(w + 2621440);
  unsigned short* Wfh  = (unsigned short*)(w + 3145728);    // 11,010,048 B
  unsigned short* Wfl  = (unsigned short*)(w + 14155776);   // 11,010,048 B
  float*          biasp= (float*)(w + 25165824);            // 16 KB
  unsigned short* xfh  = (unsigned short*)(w + 25182208);   // 20,971,520 B
  unsigned short* xfl  = (unsigned short*)(w + 46153728);   // 20,971,520 B
  unsigned short* W1fh = (unsigned short*)(w + 67125248);   // 2 MB
  unsigned short* W1fl = (unsigned short*)(w + 69222400);   // 2 MB
  float*          z    = (float*)(w + 71319552);            // 1 MB
  float*          mean = (float*)(w + 72368128);
  float*          rstd = (float*)(w + 72372224);

  zero_ws<<<512, 256, 0, stream>>>((float4*)w, 131072);
  pack_w<<<((NG / 16) * NKT * 512 + 255) / 256, 256, 0, stream>>>(W_ih, W_hh, Wfh, Wfl);
  pack_bias<<<NG / 256, 256, 0, stream>>>(b_ih, b_hh, biasp);
  pack_x<<<(SEQ * 16 * NKTX * 512 + 255) / 256, 256, 0, stream>>>(x, xfh, xfl);
  pack_w1<<<((LINEARN / 16) * NKTH * 512 + 255) / 256, 256, 0, stream>>>(W1, W1fh, W1fl);

  for (int t = 0; t < SEQ; ++t) {
    const unsigned short* hr_hi = (t & 1) ? hfh1 : hfh0;
    const unsigned short* hr_lo = (t & 1) ? hfl1 : hfl0;
    unsigned short* hw_hi = (t & 1) ? hfh0 : hfh1;
    unsigned short* hw_lo = (t & 1) ? hfl0 : hfl1;
    lstm_step<<<dim3(64, 4), 256, 0, stream>>>(
        xfh + (size_t)t * 16 * NKTX * 512, xfl + (size_t)t * 16 * NKTX * 512,
        hr_hi, hr_lo, Wfh, Wfl, biasp, cst, hw_hi, hw_lo);
  }

  // final h (t=127 odd) is in hf0
  head_gemm<<<dim3(LINEARN / 64, BATCH / 64), 256, 0, stream>>>(
      hfh0, hfl0, W1fh, W1fl, b1, z);
  bn_stats<<<LINEARN, 64, 0, stream>>>(z, mean, rstd);
  head_out<<<BATCH, 256, 0, stream>>>(z, mean, rstd, gamma, beta, W2, b2, out);
}

// Round 5
// 2790.650 us; speedup vs baseline: 1.1793x; 1.1793x over previous
//
#include <hip/hip_runtime.h>
#include <math.h>

// ---------------- constants ----------------
#define SEQ 128
#define BATCH 256
#define INPUT 300
#define HIDDEN 1024
#define NG 4096              // 4*HIDDEN, gate-interleaved: n' = 4*j + gate
#define KH 1024
#define KXP 320              // x K padded 300->320
#define KT 1344              // KH + KXP
#define NKT 42               // KT/32 k-tiles
#define KTH 32               // KH/32 h k-tiles
#define NKTH 32              // head k-tiles (K=1024)
#define LINEARN 1024

typedef __attribute__((ext_vector_type(8))) short short8;
typedef __attribute__((ext_vector_type(4))) float floatx4;

__device__ __forceinline__ float sigf(float x)     { return 1.f / (1.f + __expf(-x)); }
__device__ __forceinline__ float tanhfast(float x) { return 2.f / (1.f + __expf(-2.f * x)) - 1.f; }

__device__ __forceinline__ unsigned short bf16_rne(float f) {
  unsigned u = __float_as_uint(f);
  u += 0x7FFFu + ((u >> 16) & 1u);
  return (unsigned short)(u >> 16);
}
__device__ __forceinline__ float bf16f(unsigned short s) {
  return __uint_as_float(((unsigned)s) << 16);
}

__device__ __forceinline__ void mfma3(floatx4& acc, short8 ah, short8 al, short8 bh, short8 bl) {
  acc = __builtin_amdgcn_mfma_f32_16x16x32_bf16(ah, bh, acc, 0, 0, 0);
  acc = __builtin_amdgcn_mfma_f32_16x16x32_bf16(ah, bl, acc, 0, 0, 0);
  acc = __builtin_amdgcn_mfma_f32_16x16x32_bf16(al, bh, acc, 0, 0, 0);
}

// ---------------- zero ----------------
__global__ __launch_bounds__(256) void zero_ws(float4* p, int n4) {
  int i = blockIdx.x * 256 + threadIdx.x;
  if (i < n4) p[i] = make_float4(0.f, 0.f, 0.f, 0.f);
}

// ---------------- weight pack: gate-interleave + pad + bf16 hi/lo split ----------------
__global__ __launch_bounds__(256) void pack_w(
    const float* __restrict__ W_ih, const float* __restrict__ W_hh,
    unsigned short* __restrict__ Wph, unsigned short* __restrict__ Wpl)
{
  int id = blockIdx.x * 256 + threadIdx.x;
  if (id >= NG * KT) return;
  int n = id / KT;
  int k = id - n * KT;
  int j = n >> 2, g = n & 3;
  int srow = g * HIDDEN + j;
  float w = 0.f;
  if (k < KH) w = W_hh[(size_t)srow * HIDDEN + k];
  else if (k - KH < INPUT) w = W_ih[(size_t)srow * INPUT + (k - KH)];
  unsigned short hi = bf16_rne(w);
  Wph[id] = hi;
  Wpl[id] = bf16_rne(w - bf16f(hi));
}

__global__ __launch_bounds__(256) void pack_bias(
    const float* __restrict__ b_ih, const float* __restrict__ b_hh,
    float* __restrict__ biasp)
{
  int n = blockIdx.x * 256 + threadIdx.x;
  if (n >= NG) return;
  int j = n >> 2, g = n & 3;
  int s = g * HIDDEN + j;
  biasp[n] = b_ih[s] + b_hh[s];
}

// ---------------- pack all x timesteps to bf16 hi/lo, padded 300->320 ----------------
__global__ __launch_bounds__(256) void pack_x(
    const float* __restrict__ x, unsigned short* __restrict__ xph,
    unsigned short* __restrict__ xpl)
{
  int id = blockIdx.x * 256 + threadIdx.x;
  if (id >= SEQ * BATCH * KXP) return;
  int row = id / KXP;
  int k = id - row * KXP;
  float v = (k < INPUT) ? x[(size_t)row * INPUT + k] : 0.f;
  unsigned short hi = bf16_rne(v);
  xph[id] = hi;
  xpl[id] = bf16_rne(v - bf16f(hi));
}

// ---------------- pack W1 (head) hi/lo ----------------
__global__ __launch_bounds__(256) void pack_w1(
    const float* __restrict__ W1, unsigned short* __restrict__ W1ph,
    unsigned short* __restrict__ W1pl)
{
  int id = blockIdx.x * 256 + threadIdx.x;
  if (id >= LINEARN * HIDDEN) return;
  float w = W1[id];
  unsigned short hi = bf16_rne(w);
  W1ph[id] = hi;
  W1pl[id] = bf16_rne(w - bf16f(hi));
}

// ---------------- fused LSTM step: 32Mx64N tiles, 512 blocks (2/CU), LDS pipelined ----------------
// grid (64 jtiles, 8 mtiles), 256 threads, 4 waves: wave grid 2m x 2n, wave tile 16x32.
__global__ __launch_bounds__(256) void lstm_step(
    const unsigned short* __restrict__ xp_hi,   // [256][320] this step
    const unsigned short* __restrict__ xp_lo,
    const unsigned short* __restrict__ h_hi_r,  // [256][1024]
    const unsigned short* __restrict__ h_lo_r,
    const unsigned short* __restrict__ Wph,     // [4096][1344]
    const unsigned short* __restrict__ Wpl,
    const float* __restrict__ biasp,            // [4096]
    float* __restrict__ cst,                    // [256][1024] fp32 cell state
    unsigned short* __restrict__ h_hi_w,
    unsigned short* __restrict__ h_lo_w)
{
  // per buffer (shorts): Ah[32*40]=1280 | Al 1280 | Bh[64*40]=2560 | Bl 2560  => 7680
  __shared__ short sb[2 * 7680];   // 30.7 KB

  const int t    = threadIdx.x;
  const int lane = t & 63;
  const int wave = t >> 6;
  const int wm   = (wave >> 1) * 16;    // wave m origin within 32-row tile
  const int wn   = (wave & 1) * 32;     // wave n origin within 64-col tile
  const int col  = lane & 15;
  const int quad = lane >> 4;
  const int ra   = t >> 2;              // A staging row (t<128: 0..31)
  const int rb   = t >> 2;              // B staging row 0..63
  const int k8   = (t & 3) * 8;         // k offset {0,8,16,24} shorts
  const int m0   = blockIdx.y * 32;
  const int n0   = blockIdx.x * 64;
  const int j0   = blockIdx.x * 16;

#define LOAD_TILE(kt, AH, AL, BH, BL) do {                                   \
    if (t < 128) {                                                           \
      if ((kt) < KTH) {                                                      \
        const int ka = (kt) * 32 + k8;                                       \
        AH = *(const uint4*)(h_hi_r + (size_t)(m0 + ra) * KH + ka);          \
        AL = *(const uint4*)(h_lo_r + (size_t)(m0 + ra) * KH + ka);          \
      } else {                                                               \
        const int kx = ((kt) - KTH) * 32 + k8;                               \
        AH = *(const uint4*)(xp_hi + (size_t)(m0 + ra) * KXP + kx);          \
        AL = *(const uint4*)(xp_lo + (size_t)(m0 + ra) * KXP + kx);          \
      }                                                                      \
    }                                                                        \
    { const size_t bo = (size_t)(n0 + rb) * KT + (kt) * 32 + k8;             \
      BH = *(const uint4*)(Wph + bo);                                        \
      BL = *(const uint4*)(Wpl + bo); }                                      \
  } while (0)

#define STORE_TILE(base, AH, AL, BH, BL) do {                                \
    if (t < 128) {                                                           \
      *(uint4*)((base) +        ra * 40 + k8) = AH;                          \
      *(uint4*)((base) + 1280 + ra * 40 + k8) = AL;                          \
    }                                                                        \
    *(uint4*)((base) + 2560 + rb * 40 + k8) = BH;                            \
    *(uint4*)((base) + 5120 + rb * 40 + k8) = BL;                            \
  } while (0)

  floatx4 acc[2];
  acc[0] = (floatx4){0.f, 0.f, 0.f, 0.f};
  acc[1] = (floatx4){0.f, 0.f, 0.f, 0.f};

  uint4 cAh, cAl, cBh, cBl, nAh, nAl, nBh, nBl, tAh, tAl, tBh, tBl;
  LOAD_TILE(0, tAh, tAl, tBh, tBl);
  LOAD_TILE(1, cAh, cAl, cBh, cBl);
  STORE_TILE(sb, tAh, tAl, tBh, tBl);

  for (int kt = 0; kt < NKT; ++kt) {
    if (kt + 2 < NKT) LOAD_TILE(kt + 2, nAh, nAl, nBh, nBl);
    __syncthreads();                       // publish buf[kt&1]; prior reads done
    short* bufp = sb + (kt & 1) * 7680;

    short8 ah, al, bh[2], bl[2];
    {
      const int rowA = (wm + col) * 40 + quad * 8;
      ah = *(const short8*)(bufp + rowA);
      al = *(const short8*)(bufp + 1280 + rowA);
    }
#pragma unroll
    for (int nt = 0; nt < 2; ++nt) {
      const int rowB = (wn + nt * 16 + col) * 40 + quad * 8;
      bh[nt] = *(const short8*)(bufp + 2560 + rowB);
      bl[nt] = *(const short8*)(bufp + 5120 + rowB);
    }
    mfma3(acc[0], ah, al, bh[0], bl[0]);
    mfma3(acc[1], ah, al, bh[1], bl[1]);

    if (kt + 1 < NKT) STORE_TILE(sb + ((kt + 1) & 1) * 7680, cAh, cAl, cBh, cBl);
    cAh = nAh; cAl = nAl; cBh = nBh; cBl = nBl;
  }
#undef LOAD_TILE
#undef STORE_TILE

  // ---- epilogue: gates -> LDS [n'][m], fused cell update ----
  __syncthreads();                         // all fragment reads done before overwriting sb
  float* epi = (float*)sb;                 // [64 n'][33 m] = 8448 B
#pragma unroll
  for (int nt = 0; nt < 2; ++nt) {
    const int nl = wn + nt * 16 + col;
    const float bb = biasp[n0 + nl];
#pragma unroll
    for (int reg = 0; reg < 4; ++reg) {
      const int ml = wm + quad * 4 + reg;
      epi[nl * 33 + ml] = acc[nt][reg] + bb;
    }
  }
  __syncthreads();

  // cell: 32 m x 16 j cells; thread t: mloc = t>>3 (0..31), 2 j's at jl2=(t&7)*2
  const int mloc = t >> 3;
  const int jl2  = (t & 7) * 2;
  const int m    = m0 + mloc;
  const int j    = j0 + jl2;
  float2 cold = *(const float2*)(cst + (size_t)m * HIDDEN + j);
  float cn[2], hn[2];
#pragma unroll
  for (int jj = 0; jj < 2; ++jj) {
    const int nl = (jl2 + jj) * 4;
    const float gi = epi[(nl + 0) * 33 + mloc];
    const float gf = epi[(nl + 1) * 33 + mloc];
    const float gg = epi[(nl + 2) * 33 + mloc];
    const float go = epi[(nl + 3) * 33 + mloc];
    const float cc = jj ? cold.y : cold.x;
    const float cnew = sigf(gf) * cc + sigf(gi) * tanhfast(gg);
    cn[jj] = cnew;
    hn[jj] = sigf(go) * tanhfast(cnew);
  }
  *(float2*)(cst + (size_t)m * HIDDEN + j) = make_float2(cn[0], cn[1]);
  ushort2 uh, ul;
  uh.x = bf16_rne(hn[0]); uh.y = bf16_rne(hn[1]);
  ul.x = bf16_rne(hn[0] - bf16f(uh.x));
  ul.y = bf16_rne(hn[1] - bf16f(uh.y));
  *(ushort2*)(h_hi_w + (size_t)m * HIDDEN + j) = uh;
  *(ushort2*)(h_lo_w + (size_t)m * HIDDEN + j) = ul;
}

// ---------------- head GEMM: z = h @ W1^T + b1 (64x64 LDS pipelined) ----------------
__global__ __launch_bounds__(256) void head_gemm(
    const unsigned short* __restrict__ Ah_,     // h_hi [256][1024]
    const unsigned short* __restrict__ Al_,
    const unsigned short* __restrict__ Bh_,     // W1 hi [1024][1024]
    const unsigned short* __restrict__ Bl_,
    const float* __restrict__ bias,
    float* __restrict__ C)                      // z [256][1024]
{
  __shared__ short sb[2 * 4 * 2560];

  const int t    = threadIdx.x;
  const int lane = t & 63;
  const int wave = t >> 6;
  const int wm   = (wave >> 1) * 32;
  const int wn   = (wave & 1) * 32;
  const int col  = lane & 15;
  const int quad = lane >> 4;
  const int r    = t >> 2;
  const int k8   = (t & 3) * 8;
  const int m0   = blockIdx.y * 64;
  const int n0   = blockIdx.x * 64;

#define LOAD_TILE(kt, AH, AL, BH, BL) do {                                   \
    const int ka = (kt) * 32 + k8;                                           \
    AH = *(const uint4*)(Ah_ + (size_t)(m0 + r) * KH + ka);                  \
    AL = *(const uint4*)(Al_ + (size_t)(m0 + r) * KH + ka);                  \
    BH = *(const uint4*)(Bh_ + (size_t)(n0 + r) * KH + ka);                  \
    BL = *(const uint4*)(Bl_ + (size_t)(n0 + r) * KH + ka);                  \
  } while (0)

#define STORE_TILE(base, AH, AL, BH, BL) do {                                \
    *(uint4*)((base) +        r * 40 + k8) = AH;                             \
    *(uint4*)((base) + 2560 + r * 40 + k8) = AL;                             \
    *(uint4*)((base) + 5120 + r * 40 + k8) = BH;                             \
    *(uint4*)((base) + 7680 + r * 40 + k8) = BL;                             \
  } while (0)

  floatx4 acc[2][2];
#pragma unroll
  for (int i = 0; i < 2; ++i)
#pragma unroll
    for (int jj = 0; jj < 2; ++jj)
      acc[i][jj] = (floatx4){0.f, 0.f, 0.f, 0.f};

  uint4 cAh, cAl, cBh, cBl, nAh, nAl, nBh, nBl, tAh, tAl, tBh, tBl;
  LOAD_TILE(0, tAh, tAl, tBh, tBl);
  LOAD_TILE(1, cAh, cAl, cBh, cBl);
  STORE_TILE(sb, tAh, tAl, tBh, tBl);

  for (int kt = 0; kt < NKTH; ++kt) {
    if (kt + 2 < NKTH) LOAD_TILE(kt + 2, nAh, nAl, nBh, nBl);
    __syncthreads();
    short* bufp = sb + (kt & 1) * 10240;

    short8 ah[2], al[2], bh[2], bl[2];
#pragma unroll
    for (int mt = 0; mt < 2; ++mt) {
      const int row = (wm + mt * 16 + col) * 40 + quad * 8;
      ah[mt] = *(const short8*)(bufp + row);
      al[mt] = *(const short8*)(bufp + 2560 + row);
    }
#pragma unroll
    for (int nt = 0; nt < 2; ++nt) {
      const int row = (wn + nt * 16 + col) * 40 + quad * 8;
      bh[nt] = *(const short8*)(bufp + 5120 + row);
      bl[nt] = *(const short8*)(bufp + 7680 + row);
    }
#pragma unroll
    for (int mt = 0; mt < 2; ++mt)
#pragma unroll
      for (int nt = 0; nt < 2; ++nt)
        mfma3(acc[mt][nt], ah[mt], al[mt], bh[nt], bl[nt]);

    if (kt + 1 < NKTH) STORE_TILE(sb + ((kt + 1) & 1) * 10240, cAh, cAl, cBh, cBl);
    cAh = nAh; cAl = nAl; cBh = nBh; cBl = nBl;
  }
#undef LOAD_TILE
#undef STORE_TILE

#pragma unroll
  for (int mt = 0; mt < 2; ++mt)
#pragma unroll
    for (int nt = 0; nt < 2; ++nt) {
      const int nl = n0 + wn + nt * 16 + col;
      const float bb = bias[nl];
#pragma unroll
      for (int reg = 0; reg < 4; ++reg) {
        const int ml = m0 + wm + mt * 16 + quad * 4 + reg;
        C[(size_t)ml * LINEARN + nl] = acc[mt][nt][reg] + bb;
      }
    }
}

// ---------------- BN stats ----------------
__global__ __launch_bounds__(64) void bn_stats(
    const float* __restrict__ z, float* __restrict__ mean, float* __restrict__ rstd)
{
  const int n = blockIdx.x;
  const int t = threadIdx.x;
  float s = 0.f, s2 = 0.f;
  for (int r = t; r < BATCH; r += 64) {
    const float v = z[(size_t)r * LINEARN + n];
    s += v; s2 += v * v;
  }
#pragma unroll
  for (int off = 32; off > 0; off >>= 1) {
    s  += __shfl_down(s,  off, 64);
    s2 += __shfl_down(s2, off, 64);
  }
  if (t == 0) {
    const float mm = s * (1.f / BATCH);
    mean[n] = mm;
    rstd[n] = rsqrtf(s2 * (1.f / BATCH) - mm * mm + 1e-5f);
  }
}

// ---------------- head out ----------------
__global__ __launch_bounds__(256) void head_out(
    const float* __restrict__ z, const float* __restrict__ mean, const float* __restrict__ rstd,
    const float* __restrict__ gamma, const float* __restrict__ beta,
    const float* __restrict__ W2, const float* __restrict__ b2, float* __restrict__ out)
{
  const int b = blockIdx.x;
  const int t = threadIdx.x;
  float acc = 0.f;
  for (int n = t; n < LINEARN; n += 256) {
    float v = (z[(size_t)b * LINEARN + n] - mean[n]) * rstd[n] * gamma[n] + beta[n];
    v = fmaxf(v, 0.f);
    acc += v * W2[n];
  }
#pragma unroll
  for (int off = 32; off > 0; off >>= 1) acc += __shfl_down(acc, off, 64);
  __shared__ float ls[4];
  if ((t & 63) == 0) ls[t >> 6] = acc;
  __syncthreads();
  if (t == 0) {
    const float tot = ls[0] + ls[1] + ls[2] + ls[3] + b2[0];
    out[b] = 3.f / (1.f + __expf(-tot));
  }
}

// ---------------- launch ----------------
extern "C" void kernel_launch(void* const* d_in, const int* in_sizes, int n_in,
                              void* d_out, int out_size, void* d_ws, size_t ws_size,
                              hipStream_t stream) {
  const float* x     = (const float*)d_in[0];
  const float* W_ih  = (const float*)d_in[1];
  const float* W_hh  = (const float*)d_in[2];
  const float* b_ih  = (const float*)d_in[3];
  const float* b_hh  = (const float*)d_in[4];
  const float* W1    = (const float*)d_in[5];
  const float* b1    = (const float*)d_in[6];
  const float* gamma = (const float*)d_in[7];
  const float* beta  = (const float*)d_in[8];
  const float* W2    = (const float*)d_in[9];
  const float* b2    = (const float*)d_in[10];
  float* out = (float*)d_out;

  char* w = (char*)d_ws;
  // zero region (contiguous 2 MB): h_hi0, h_lo0, c
  unsigned short* h_hi0 = (unsigned short*)(w + 0);
  unsigned short* h_lo0 = (unsigned short*)(w + 524288);
  float*          cst   = (float*)(w + 1048576);
  unsigned short* h_hi1 = (unsigned short*)(w + 2097152);
  unsigned short* h_lo1 = (unsigned short*)(w + 2621440);
  unsigned short* Wph   = (unsigned short*)(w + 3145728);    // 11,010,048 B
  unsigned short* Wpl   = (unsigned short*)(w + 14155776);   // 11,010,048 B
  float*          biasp = (float*)(w + 25165824);            // 16 KB
  unsigned short* xph   = (unsigned short*)(w + 25182208);   // 20,971,520 B
  unsigned short* xpl   = (unsigned short*)(w + 46153728);   // 20,971,520 B
  unsigned short* W1ph  = (unsigned short*)(w + 67125248);   // 2 MB
  unsigned short* W1pl  = (unsigned short*)(w + 69222400);   // 2 MB
  float*          z     = (float*)(w + 71319552);            // 1 MB
  float*          mean  = (float*)(w + 72368128);
  float*          rstd  = (float*)(w + 72372224);

  zero_ws<<<512, 256, 0, stream>>>((float4*)w, 131072);
  pack_w<<<(NG * KT + 255) / 256, 256, 0, stream>>>(W_ih, W_hh, Wph, Wpl);
  pack_bias<<<NG / 256, 256, 0, stream>>>(b_ih, b_hh, biasp);
  pack_x<<<(SEQ * BATCH * KXP + 255) / 256, 256, 0, stream>>>(x, xph, xpl);
  pack_w1<<<(LINEARN * HIDDEN + 255) / 256, 256, 0, stream>>>(W1, W1ph, W1pl);

  for (int t = 0; t < SEQ; ++t) {
    const unsigned short* hr_hi = (t & 1) ? h_hi1 : h_hi0;
    const unsigned short* hr_lo = (t & 1) ? h_lo1 : h_lo0;
    unsigned short* hw_hi = (t & 1) ? h_hi0 : h_hi1;
    unsigned short* hw_lo = (t & 1) ? h_lo0 : h_lo1;
    lstm_step<<<dim3(64, 8), 256, 0, stream>>>(
        xph + (size_t)t * BATCH * KXP, xpl + (size_t)t * BATCH * KXP,
        hr_hi, hr_lo, Wph, Wpl, biasp, cst, hw_hi, hw_lo);
  }

  // final h (t=127 odd) is in h_hi0/h_lo0
  head_gemm<<<dim3(LINEARN / 64, BATCH / 64), 256, 0, stream>>>(
      h_hi0, h_lo0, W1ph, W1pl, b1, z);
  bn_stats<<<LINEARN, 64, 0, stream>>>(z, mean, rstd);
  head_out<<<BATCH, 256, 0, stream>>>(z, mean, rstd, gamma, beta, W2, b2, out);
}

// Round 6
// 2342.943 us; speedup vs baseline: 1.4046x; 1.1911x over previous
//
#include <hip/hip_runtime.h>
#include <math.h>

// ---------------- constants ----------------
#define SEQ 128
#define BATCH 256
#define INPUT 300
#define HIDDEN 1024
#define NG 4096              // 4*HIDDEN, gate-interleaved: n' = 4*j + gate
#define KH 1024
#define KXP 320              // x K padded 300->320
#define KT 1344              // KH + KXP
#define NKT 42               // KT/32 k-tiles
#define KTH 32               // KH/32 h k-tiles
#define NKTH 32              // head k-tiles (K=1024)
#define LINEARN 1024

typedef __attribute__((ext_vector_type(8))) short short8;
typedef __attribute__((ext_vector_type(4))) float floatx4;

__device__ __forceinline__ float sigf(float x)     { return 1.f / (1.f + __expf(-x)); }
__device__ __forceinline__ float tanhfast(float x) { return 2.f / (1.f + __expf(-2.f * x)) - 1.f; }

__device__ __forceinline__ unsigned short bf16_rne(float f) {
  unsigned u = __float_as_uint(f);
  u += 0x7FFFu + ((u >> 16) & 1u);
  return (unsigned short)(u >> 16);
}
__device__ __forceinline__ float bf16f(unsigned short s) {
  return __uint_as_float(((unsigned)s) << 16);
}

__device__ __forceinline__ void mfma3(floatx4& acc, short8 ah, short8 al, short8 bh, short8 bl) {
  acc = __builtin_amdgcn_mfma_f32_16x16x32_bf16(ah, bh, acc, 0, 0, 0);
  acc = __builtin_amdgcn_mfma_f32_16x16x32_bf16(ah, bl, acc, 0, 0, 0);
  acc = __builtin_amdgcn_mfma_f32_16x16x32_bf16(al, bh, acc, 0, 0, 0);
}
// W kept at bf16 (hi only); A split hi/lo corrects the h/x quantization.
__device__ __forceinline__ void mfma2(floatx4& acc, short8 ah, short8 al, short8 bh) {
  acc = __builtin_amdgcn_mfma_f32_16x16x32_bf16(ah, bh, acc, 0, 0, 0);
  acc = __builtin_amdgcn_mfma_f32_16x16x32_bf16(al, bh, acc, 0, 0, 0);
}

// ---------------- zero ----------------
__global__ __launch_bounds__(256) void zero_ws(float4* p, int n4) {
  int i = blockIdx.x * 256 + threadIdx.x;
  if (i < n4) p[i] = make_float4(0.f, 0.f, 0.f, 0.f);
}

// ---------------- weight pack: gate-interleave + pad, bf16 hi only ----------------
__global__ __launch_bounds__(256) void pack_w(
    const float* __restrict__ W_ih, const float* __restrict__ W_hh,
    unsigned short* __restrict__ Wph)
{
  int id = blockIdx.x * 256 + threadIdx.x;
  if (id >= NG * KT) return;
  int n = id / KT;
  int k = id - n * KT;
  int j = n >> 2, g = n & 3;
  int srow = g * HIDDEN + j;
  float w = 0.f;
  if (k < KH) w = W_hh[(size_t)srow * HIDDEN + k];
  else if (k - KH < INPUT) w = W_ih[(size_t)srow * INPUT + (k - KH)];
  Wph[id] = bf16_rne(w);
}

__global__ __launch_bounds__(256) void pack_bias(
    const float* __restrict__ b_ih, const float* __restrict__ b_hh,
    float* __restrict__ biasp)
{
  int n = blockIdx.x * 256 + threadIdx.x;
  if (n >= NG) return;
  int j = n >> 2, g = n & 3;
  int s = g * HIDDEN + j;
  biasp[n] = b_ih[s] + b_hh[s];
}

// ---------------- pack all x timesteps to bf16 hi/lo, padded 300->320 ----------------
__global__ __launch_bounds__(256) void pack_x(
    const float* __restrict__ x, unsigned short* __restrict__ xph,
    unsigned short* __restrict__ xpl)
{
  int id = blockIdx.x * 256 + threadIdx.x;
  if (id >= SEQ * BATCH * KXP) return;
  int row = id / KXP;
  int k = id - row * KXP;
  float v = (k < INPUT) ? x[(size_t)row * INPUT + k] : 0.f;
  unsigned short hi = bf16_rne(v);
  xph[id] = hi;
  xpl[id] = bf16_rne(v - bf16f(hi));
}

// ---------------- pack W1 (head) hi/lo ----------------
__global__ __launch_bounds__(256) void pack_w1(
    const float* __restrict__ W1, unsigned short* __restrict__ W1ph,
    unsigned short* __restrict__ W1pl)
{
  int id = blockIdx.x * 256 + threadIdx.x;
  if (id >= LINEARN * HIDDEN) return;
  float w = W1[id];
  unsigned short hi = bf16_rne(w);
  W1ph[id] = hi;
  W1pl[id] = bf16_rne(w - bf16f(hi));
}

// ---------------- fused LSTM step: 64x64 tiles, XCD-swizzled, W bf16-hi, LDS pipelined ----------------
// grid 256 linear blocks; swizzle: XCD (id%8) owns jtiles [8k,8k+8) for all 4 mtiles,
// so each XCD's W working set (~1.4 MB hi) + A (~1.3 MB) stays L2-resident across steps.
__global__ __launch_bounds__(256) void lstm_step(
    const unsigned short* __restrict__ xp_hi,   // [256][320] this step
    const unsigned short* __restrict__ xp_lo,
    const unsigned short* __restrict__ h_hi_r,  // [256][1024]
    const unsigned short* __restrict__ h_lo_r,
    const unsigned short* __restrict__ Wph,     // [4096][1344] bf16 hi
    const float* __restrict__ biasp,            // [4096]
    float* __restrict__ cst,                    // [256][1024] fp32 cell state
    unsigned short* __restrict__ h_hi_w,
    unsigned short* __restrict__ h_lo_w)
{
  // per buffer (shorts): Ah[64*40]=2560 | Al 2560 | Bh 2560 => 7680 (x2 = 30.7 KB)
  __shared__ short sb[2 * 7680];

  const int t    = threadIdx.x;
  const int lane = t & 63;
  const int wave = t >> 6;
  const int wm   = (wave >> 1) * 32;
  const int wn   = (wave & 1) * 32;
  const int col  = lane & 15;
  const int quad = lane >> 4;
  const int r    = t >> 2;              // staging row 0..63
  const int k8   = (t & 3) * 8;         // k offset {0,8,16,24} shorts
  const int id     = blockIdx.x;
  const int jtile  = (id & 7) * 8 + ((id >> 3) & 7);   // XCD-local j grouping
  const int mt_    = id >> 6;                          // 0..3
  const int m0   = mt_ * 64;
  const int n0   = jtile * 64;
  const int j0   = jtile * 16;

#define LOAD_TILE(kt, AH, AL, BH) do {                                       \
    if ((kt) < KTH) {                                                        \
      const int ka = (kt) * 32 + k8;                                         \
      AH = *(const uint4*)(h_hi_r + (size_t)(m0 + r) * KH + ka);             \
      AL = *(const uint4*)(h_lo_r + (size_t)(m0 + r) * KH + ka);             \
    } else {                                                                 \
      const int kx = ((kt) - KTH) * 32 + k8;                                 \
      AH = *(const uint4*)(xp_hi + (size_t)(m0 + r) * KXP + kx);             \
      AL = *(const uint4*)(xp_lo + (size_t)(m0 + r) * KXP + kx);             \
    }                                                                        \
    BH = *(const uint4*)(Wph + (size_t)(n0 + r) * KT + (kt) * 32 + k8);      \
  } while (0)

#define STORE_TILE(base, AH, AL, BH) do {                                    \
    *(uint4*)((base) +        r * 40 + k8) = AH;                             \
    *(uint4*)((base) + 2560 + r * 40 + k8) = AL;                             \
    *(uint4*)((base) + 5120 + r * 40 + k8) = BH;                             \
  } while (0)

  floatx4 acc[2][2];
#pragma unroll
  for (int i = 0; i < 2; ++i)
#pragma unroll
    for (int jj = 0; jj < 2; ++jj)
      acc[i][jj] = (floatx4){0.f, 0.f, 0.f, 0.f};

  uint4 cAh, cAl, cBh, nAh, nAl, nBh, tAh, tAl, tBh;
  LOAD_TILE(0, tAh, tAl, tBh);
  LOAD_TILE(1, cAh, cAl, cBh);
  STORE_TILE(sb, tAh, tAl, tBh);

  for (int kt = 0; kt < NKT; ++kt) {
    if (kt + 2 < NKT) LOAD_TILE(kt + 2, nAh, nAl, nBh);
    __syncthreads();                       // publish buf[kt&1]; prior reads done
    short* bufp = sb + (kt & 1) * 7680;

    short8 ah[2], al[2], bh[2];
#pragma unroll
    for (int mt = 0; mt < 2; ++mt) {
      const int row = (wm + mt * 16 + col) * 40 + quad * 8;
      ah[mt] = *(const short8*)(bufp + row);
      al[mt] = *(const short8*)(bufp + 2560 + row);
    }
#pragma unroll
    for (int nt = 0; nt < 2; ++nt) {
      const int row = (wn + nt * 16 + col) * 40 + quad * 8;
      bh[nt] = *(const short8*)(bufp + 5120 + row);
    }
#pragma unroll
    for (int mt = 0; mt < 2; ++mt)
#pragma unroll
      for (int nt = 0; nt < 2; ++nt)
        mfma2(acc[mt][nt], ah[mt], al[mt], bh[nt]);

    if (kt + 1 < NKT) STORE_TILE(sb + ((kt + 1) & 1) * 7680, cAh, cAl, cBh);
    cAh = nAh; cAl = nAl; cBh = nBh;
  }
#undef LOAD_TILE
#undef STORE_TILE

  // ---- epilogue: gates -> LDS [n'][m], fused cell update ----
  __syncthreads();
  float* epi = (float*)sb;   // 64*65 floats = 16.6 KB <= 30.7 KB
#pragma unroll
  for (int mt = 0; mt < 2; ++mt)
#pragma unroll
    for (int nt = 0; nt < 2; ++nt) {
      const int nl = wn + nt * 16 + col;
      const float bb = biasp[n0 + nl];
#pragma unroll
      for (int reg = 0; reg < 4; ++reg) {
        const int ml = wm + mt * 16 + quad * 4 + reg;
        epi[nl * 65 + ml] = acc[mt][nt][reg] + bb;
      }
    }
  __syncthreads();

  const int mloc = t >> 2;
  const int jl4  = (t & 3) * 4;
  const int m    = m0 + mloc;
  const int j    = j0 + jl4;
  float4 cold = *(const float4*)(cst + (size_t)m * HIDDEN + j);
  float cn[4], hn[4];
#pragma unroll
  for (int jj = 0; jj < 4; ++jj) {
    const int nl = (jl4 + jj) * 4;
    const float gi = epi[(nl + 0) * 65 + mloc];
    const float gf = epi[(nl + 1) * 65 + mloc];
    const float gg = epi[(nl + 2) * 65 + mloc];
    const float go = epi[(nl + 3) * 65 + mloc];
    const float cc = (jj == 0) ? cold.x : (jj == 1) ? cold.y : (jj == 2) ? cold.z : cold.w;
    const float cnew = sigf(gf) * cc + sigf(gi) * tanhfast(gg);
    cn[jj] = cnew;
    hn[jj] = sigf(go) * tanhfast(cnew);
  }
  *(float4*)(cst + (size_t)m * HIDDEN + j) = make_float4(cn[0], cn[1], cn[2], cn[3]);
  ushort4 uh, ul;
  uh.x = bf16_rne(hn[0]); uh.y = bf16_rne(hn[1]); uh.z = bf16_rne(hn[2]); uh.w = bf16_rne(hn[3]);
  ul.x = bf16_rne(hn[0] - bf16f(uh.x));
  ul.y = bf16_rne(hn[1] - bf16f(uh.y));
  ul.z = bf16_rne(hn[2] - bf16f(uh.z));
  ul.w = bf16_rne(hn[3] - bf16f(uh.w));
  *(ushort4*)(h_hi_w + (size_t)m * HIDDEN + j) = uh;
  *(ushort4*)(h_lo_w + (size_t)m * HIDDEN + j) = ul;
}

// ---------------- head GEMM: z = h @ W1^T + b1 (64x64 LDS pipelined, 3-MFMA) ----------------
__global__ __launch_bounds__(256) void head_gemm(
    const unsigned short* __restrict__ Ah_,     // h_hi [256][1024]
    const unsigned short* __restrict__ Al_,
    const unsigned short* __restrict__ Bh_,     // W1 hi [1024][1024]
    const unsigned short* __restrict__ Bl_,
    const float* __restrict__ bias,
    float* __restrict__ C)                      // z [256][1024]
{
  __shared__ short sb[2 * 4 * 2560];

  const int t    = threadIdx.x;
  const int lane = t & 63;
  const int wave = t >> 6;
  const int wm   = (wave >> 1) * 32;
  const int wn   = (wave & 1) * 32;
  const int col  = lane & 15;
  const int quad = lane >> 4;
  const int r    = t >> 2;
  const int k8   = (t & 3) * 8;
  const int m0   = blockIdx.y * 64;
  const int n0   = blockIdx.x * 64;

#define LOAD_TILE(kt, AH, AL, BH, BL) do {                                   \
    const int ka = (kt) * 32 + k8;                                           \
    AH = *(const uint4*)(Ah_ + (size_t)(m0 + r) * KH + ka);                  \
    AL = *(const uint4*)(Al_ + (size_t)(m0 + r) * KH + ka);                  \
    BH = *(const uint4*)(Bh_ + (size_t)(n0 + r) * KH + ka);                  \
    BL = *(const uint4*)(Bl_ + (size_t)(n0 + r) * KH + ka);                  \
  } while (0)

#define STORE_TILE(base, AH, AL, BH, BL) do {                                \
    *(uint4*)((base) +        r * 40 + k8) = AH;                             \
    *(uint4*)((base) + 2560 + r * 40 + k8) = AL;                             \
    *(uint4*)((base) + 5120 + r * 40 + k8) = BH;                             \
    *(uint4*)((base) + 7680 + r * 40 + k8) = BL;                             \
  } while (0)

  floatx4 acc[2][2];
#pragma unroll
  for (int i = 0; i < 2; ++i)
#pragma unroll
    for (int jj = 0; jj < 2; ++jj)
      acc[i][jj] = (floatx4){0.f, 0.f, 0.f, 0.f};

  uint4 cAh, cAl, cBh, cBl, nAh, nAl, nBh, nBl, tAh, tAl, tBh, tBl;
  LOAD_TILE(0, tAh, tAl, tBh, tBl);
  LOAD_TILE(1, cAh, cAl, cBh, cBl);
  STORE_TILE(sb, tAh, tAl, tBh, tBl);

  for (int kt = 0; kt < NKTH; ++kt) {
    if (kt + 2 < NKTH) LOAD_TILE(kt + 2, nAh, nAl, nBh, nBl);
    __syncthreads();
    short* bufp = sb + (kt & 1) * 10240;

    short8 ah[2], al[2], bh[2], bl[2];
#pragma unroll
    for (int mt = 0; mt < 2; ++mt) {
      const int row = (wm + mt * 16 + col) * 40 + quad * 8;
      ah[mt] = *(const short8*)(bufp + row);
      al[mt] = *(const short8*)(bufp + 2560 + row);
    }
#pragma unroll
    for (int nt = 0; nt < 2; ++nt) {
      const int row = (wn + nt * 16 + col) * 40 + quad * 8;
      bh[nt] = *(const short8*)(bufp + 5120 + row);
      bl[nt] = *(const short8*)(bufp + 7680 + row);
    }
#pragma unroll
    for (int mt = 0; mt < 2; ++mt)
#pragma unroll
      for (int nt = 0; nt < 2; ++nt)
        mfma3(acc[mt][nt], ah[mt], al[mt], bh[nt], bl[nt]);

    if (kt + 1 < NKTH) STORE_TILE(sb + ((kt + 1) & 1) * 10240, cAh, cAl, cBh, cBl);
    cAh = nAh; cAl = nAl; cBh = nBh; cBl = nBl;
  }
#undef LOAD_TILE
#undef STORE_TILE

#pragma unroll
  for (int mt = 0; mt < 2; ++mt)
#pragma unroll
    for (int nt = 0; nt < 2; ++nt) {
      const int nl = n0 + wn + nt * 16 + col;
      const float bb = bias[nl];
#pragma unroll
      for (int reg = 0; reg < 4; ++reg) {
        const int ml = m0 + wm + mt * 16 + quad * 4 + reg;
        C[(size_t)ml * LINEARN + nl] = acc[mt][nt][reg] + bb;
      }
    }
}

// ---------------- BN stats ----------------
__global__ __launch_bounds__(64) void bn_stats(
    const float* __restrict__ z, float* __restrict__ mean, float* __restrict__ rstd)
{
  const int n = blockIdx.x;
  const int t = threadIdx.x;
  float s = 0.f, s2 = 0.f;
  for (int r = t; r < BATCH; r += 64) {
    const float v = z[(size_t)r * LINEARN + n];
    s += v; s2 += v * v;
  }
#pragma unroll
  for (int off = 32; off > 0; off >>= 1) {
    s  += __shfl_down(s,  off, 64);
    s2 += __shfl_down(s2, off, 64);
  }
  if (t == 0) {
    const float mm = s * (1.f / BATCH);
    mean[n] = mm;
    rstd[n] = rsqrtf(s2 * (1.f / BATCH) - mm * mm + 1e-5f);
  }
}

// ---------------- head out ----------------
__global__ __launch_bounds__(256) void head_out(
    const float* __restrict__ z, const float* __restrict__ mean, const float* __restrict__ rstd,
    const float* __restrict__ gamma, const float* __restrict__ beta,
    const float* __restrict__ W2, const float* __restrict__ b2, float* __restrict__ out)
{
  const int b = blockIdx.x;
  const int t = threadIdx.x;
  float acc = 0.f;
  for (int n = t; n < LINEARN; n += 256) {
    float v = (z[(size_t)b * LINEARN + n] - mean[n]) * rstd[n] * gamma[n] + beta[n];
    v = fmaxf(v, 0.f);
    acc += v * W2[n];
  }
#pragma unroll
  for (int off = 32; off > 0; off >>= 1) acc += __shfl_down(acc, off, 64);
  __shared__ float ls[4];
  if ((t & 63) == 0) ls[t >> 6] = acc;
  __syncthreads();
  if (t == 0) {
    const float tot = ls[0] + ls[1] + ls[2] + ls[3] + b2[0];
    out[b] = 3.f / (1.f + __expf(-tot));
  }
}

// ---------------- launch ----------------
extern "C" void kernel_launch(void* const* d_in, const int* in_sizes, int n_in,
                              void* d_out, int out_size, void* d_ws, size_t ws_size,
                              hipStream_t stream) {
  const float* x     = (const float*)d_in[0];
  const float* W_ih  = (const float*)d_in[1];
  const float* W_hh  = (const float*)d_in[2];
  const float* b_ih  = (const float*)d_in[3];
  const float* b_hh  = (const float*)d_in[4];
  const float* W1    = (const float*)d_in[5];
  const float* b1    = (const float*)d_in[6];
  const float* gamma = (const float*)d_in[7];
  const float* beta  = (const float*)d_in[8];
  const float* W2    = (const float*)d_in[9];
  const float* b2    = (const float*)d_in[10];
  float* out = (float*)d_out;

  char* w = (char*)d_ws;
  // zero region (contiguous 2 MB): h_hi0, h_lo0, c
  unsigned short* h_hi0 = (unsigned short*)(w + 0);          // 512 KB
  unsigned short* h_lo0 = (unsigned short*)(w + 524288);     // 512 KB
  float*          cst   = (float*)(w + 1048576);             // 1 MB
  unsigned short* h_hi1 = (unsigned short*)(w + 2097152);
  unsigned short* h_lo1 = (unsigned short*)(w + 2621440);
  unsigned short* Wph   = (unsigned short*)(w + 3145728);    // 11,010,048 B
  float*          biasp = (float*)(w + 14155776);            // 16 KB
  unsigned short* xph   = (unsigned short*)(w + 14172160);   // 20,971,520 B
  unsigned short* xpl   = (unsigned short*)(w + 35143680);   // 20,971,520 B
  unsigned short* W1ph  = (unsigned short*)(w + 56115200);   // 2 MB
  unsigned short* W1pl  = (unsigned short*)(w + 58212352);   // 2 MB
  float*          z     = (float*)(w + 60309504);            // 1 MB
  float*          mean  = (float*)(w + 61358080);
  float*          rstd  = (float*)(w + 61362176);

  zero_ws<<<512, 256, 0, stream>>>((float4*)w, 131072);
  pack_w<<<(NG * KT + 255) / 256, 256, 0, stream>>>(W_ih, W_hh, Wph);
  pack_bias<<<NG / 256, 256, 0, stream>>>(b_ih, b_hh, biasp);
  pack_x<<<(SEQ * BATCH * KXP + 255) / 256, 256, 0, stream>>>(x, xph, xpl);
  pack_w1<<<(LINEARN * HIDDEN + 255) / 256, 256, 0, stream>>>(W1, W1ph, W1pl);

  for (int t = 0; t < SEQ; ++t) {
    const unsigned short* hr_hi = (t & 1) ? h_hi1 : h_hi0;
    const unsigned short* hr_lo = (t & 1) ? h_lo1 : h_lo0;
    unsigned short* hw_hi = (t & 1) ? h_hi0 : h_hi1;
    unsigned short* hw_lo = (t & 1) ? h_lo0 : h_lo1;
    lstm_step<<<256, 256, 0, stream>>>(
        xph + (size_t)t * BATCH * KXP, xpl + (size_t)t * BATCH * KXP,
        hr_hi, hr_lo, Wph, biasp, cst, hw_hi, hw_lo);
  }

  // final h (t=127 odd) is in h_hi0/h_lo0
  head_gemm<<<dim3(LINEARN / 64, BATCH / 64), 256, 0, stream>>>(
      h_hi0, h_lo0, W1ph, W1pl, b1, z);
  bn_stats<<<LINEARN, 64, 0, stream>>>(z, mean, rstd);
  head_out<<<BATCH, 256, 0, stream>>>(z, mean, rstd, gamma, beta, W2, b2, out);
}